// Round 12
// baseline (274.105 us; speedup 1.0000x reference)
//
#include <hip/hip_runtime.h>

#define LNUM 8
#define WD 128
#define BATCH 262144

typedef unsigned int u32;
typedef __attribute__((ext_vector_type(8))) short bf16x8;
typedef __attribute__((ext_vector_type(4))) float f32x4;

// packed f32x2 -> bf16x2 (single VALU op; validated R4+)
__device__ __forceinline__ u32 pk2(float x, float y){
  u32 r;
  asm("v_cvt_pk_bf16_f32 %0, %1, %2" : "=v"(r) : "v"(x), "v"(y));
  return r;
}

// NATURAL-order W image (mid1 k-map). Row-major bf16, XOR-swizzled 4-dword.
// 256 threads: row j=t>>1, half h=t&1. Validated R2/R3/R10/R11.
__device__ __forceinline__ void stage_Wnat(const float* __restrict__ src, u32* dst, int tid){
  const int j = tid >> 1, h = tid & 1;
  const float* s = src + j * WD + h * 64;
  u32* drow = dst + j * 64;
  const int base = h * 32;
  const u32 sz = (u32)((j & 7) << 2);
#pragma unroll
  for(int c = 0; c < 8; ++c){
    float4 f0 = *(const float4*)(s + c * 8);
    float4 f1 = *(const float4*)(s + c * 8 + 4);
    uint4 w;
    w.x = pk2(f0.x, f0.y); w.y = pk2(f0.z, f0.w);
    w.z = pk2(f1.x, f1.y); w.w = pk2(f1.z, f1.w);
    *(uint4*)(drow + (((u32)(base + c * 4)) ^ sz)) = w;
  }
}

// PERMUTED fragment-contiguous W image (mid2 k-map
// slot(lg,e) <-> k = kt*32+(e>>2)*16+lg*4+(e&3)): A-fragment for (lg,kt) is
// ONE b128 at dword (kt*16+lg*4)^sz. Validated R9/R10/R11.
__device__ __forceinline__ void stage_Wperm(const float* __restrict__ src, u32* dst, int tid){
  const int j = tid >> 1, h = tid & 1;
  const float* srow = src + j * WD;
  u32* drow = dst + j * 64;
  const u32 sz = (u32)((j & 7) << 2);
#pragma unroll
  for(int kk = 0; kk < 2; ++kk){
    const int kt = 2 * h + kk;
#pragma unroll
    for(int g = 0; g < 4; ++g){
      float4 f0 = *(const float4*)(srow + kt * 32 + g * 4);
      float4 f1 = *(const float4*)(srow + kt * 32 + 16 + g * 4);
      uint4 w;
      w.x = pk2(f0.x, f0.y); w.y = pk2(f0.z, f0.w);
      w.z = pk2(f1.x, f1.y); w.w = pk2(f1.z, f1.w);
      *(uint4*)(drow + (((u32)(kt * 16 + g * 4)) ^ sz)) = w;
    }
  }
}

// DMA a 16384-dword (two-matrix) slab from the preprocessed global image into
// LDS. global_load_lds: per-lane GLOBAL src, wave-uniform LDS base + lane*16.
__device__ __forceinline__ void stage_dma(const u32* __restrict__ g, u32* l, int wv, int lane){
#pragma unroll
  for(int it = 0; it < 8; ++it){
    const int o = wv * 2048 + it * 256;
    __builtin_amdgcn_global_load_lds(
        (const __attribute__((address_space(1))) u32*)(g + o + lane * 4),
        (__attribute__((address_space(3))) u32*)(l + o),
        16, 0, 0);
  }
}

// ---- stage-1 B-fragment pack: one sample-subtile (st), k-chunk kt ----
#define PACK_ST(dstv, uv) do { \
    uint4 pk_; \
    pk_.x = pk2(fmaxf(fmaf(uv, w1a_.x, g1a_.x), 0.f), fmaxf(fmaf(uv, w1a_.y, g1a_.y), 0.f)); \
    pk_.y = pk2(fmaxf(fmaf(uv, w1a_.z, g1a_.z), 0.f), fmaxf(fmaf(uv, w1a_.w, g1a_.w), 0.f)); \
    pk_.z = pk2(fmaxf(fmaf(uv, w1b_.x, g1b_.x), 0.f), fmaxf(fmaf(uv, w1b_.y, g1b_.y), 0.f)); \
    pk_.w = pk2(fmaxf(fmaf(uv, w1b_.z, g1b_.z), 0.f), fmaxf(fmaf(uv, w1b_.w, g1b_.w), 0.f)); \
    dstv = __builtin_bit_cast(bf16x8, pk_); \
  } while(0)

#define PACK_BV(buf, ktc) do { \
    const int ko_ = (ktc) * 32 + lg * 8; \
    const float4 w1a_ = *(const float4*)(W1 + ko_); \
    const float4 w1b_ = *(const float4*)(W1 + ko_ + 4); \
    const float4 g1a_ = *(const float4*)(b1 + ko_); \
    const float4 g1b_ = *(const float4*)(b1 + ko_ + 4); \
    PACK_ST((buf)[0], us0); PACK_ST((buf)[1], us1); \
    PACK_ST((buf)[2], us2); PACK_ST((buf)[3], us3); \
  } while(0)

// ---- stage-4 fold of one finished mid2 j-tile (delayed one iteration) ----
#define FOLD(jtc) do { \
    const float4 wc_ = *(const float4*)(W4 + (jtc) * 16 + lg * 4); \
    p0 = fmaf(fmaxf(aa[(jtc)&1][0][0], 0.f), wc_.x, p0); \
    p0 = fmaf(fmaxf(aa[(jtc)&1][0][1], 0.f), wc_.y, p0); \
    p0 = fmaf(fmaxf(aa[(jtc)&1][0][2], 0.f), wc_.z, p0); \
    p0 = fmaf(fmaxf(aa[(jtc)&1][0][3], 0.f), wc_.w, p0); \
    p1 = fmaf(fmaxf(aa[(jtc)&1][1][0], 0.f), wc_.x, p1); \
    p1 = fmaf(fmaxf(aa[(jtc)&1][1][1], 0.f), wc_.y, p1); \
    p1 = fmaf(fmaxf(aa[(jtc)&1][1][2], 0.f), wc_.z, p1); \
    p1 = fmaf(fmaxf(aa[(jtc)&1][1][3], 0.f), wc_.w, p1); \
    p2 = fmaf(fmaxf(aa[(jtc)&1][2][0], 0.f), wc_.x, p2); \
    p2 = fmaf(fmaxf(aa[(jtc)&1][2][1], 0.f), wc_.y, p2); \
    p2 = fmaf(fmaxf(aa[(jtc)&1][2][2], 0.f), wc_.z, p2); \
    p2 = fmaf(fmaxf(aa[(jtc)&1][2][3], 0.f), wc_.w, p2); \
    p3 = fmaf(fmaxf(aa[(jtc)&1][3][0], 0.f), wc_.x, p3); \
    p3 = fmaf(fmaxf(aa[(jtc)&1][3][1], 0.f), wc_.y, p3); \
    p3 = fmaf(fmaxf(aa[(jtc)&1][3][2], 0.f), wc_.z, p3); \
    p3 = fmaf(fmaxf(aa[(jtc)&1][3][3], 0.f), wc_.w, p3); \
  } while(0)

// Full 4-stage MLP for the wave's 64 samples. Same math/k-maps as R10/R11
// (absmax-validated), restructured for MFMA||VALU overlap:
//   mid1: bv double-buffered, pack[kt+1] issued ahead of MFMA cluster[kt];
//   transition packs straight into mid2 B-operand layout trq[kt][st];
//   mid2: acc double-buffered, fold[jt-1] interleaved with MFMA cluster[jt].
__device__ __forceinline__ float mlp_full(
    float u, const u32* __restrict__ W2lds, const u32* __restrict__ W3lds,
    const float* __restrict__ W1, const float* __restrict__ b1,
    const float* __restrict__ b2, const float* __restrict__ b3,
    const float* __restrict__ W4, int lm, int lg)
{
  const float us0 = __shfl(u, lm, 64);
  const float us1 = __shfl(u, 16 + lm, 64);
  const float us2 = __shfl(u, 32 + lm, 64);
  const float us3 = __shfl(u, 48 + lm, 64);

  // acc1 C-init = b2 (m89 D-map row j = jt*16 + lg*4 + reg)
  f32x4 acc1[8][4];
#pragma unroll
  for(int jt = 0; jt < 8; ++jt){
    const float4 bb = *(const float4*)(b2 + jt * 16 + lg * 4);
    const f32x4 binit = {bb.x, bb.y, bb.z, bb.w};
#pragma unroll
    for(int st = 0; st < 4; ++st) acc1[jt][st] = binit;
  }

  // ---- stage1 + mid1, software-pipelined ----
  bf16x8 bv[2][4];
  PACK_BV(bv[0], 0);
#pragma unroll
  for(int kt = 0; kt < 4; ++kt){
    if(kt < 3) PACK_BV(bv[(kt + 1) & 1], kt + 1);   // next pack ahead of MFMAs
    const u32 kdw = (u32)(kt * 16 + lg * 4);
    __builtin_amdgcn_s_setprio(1);
#pragma unroll
    for(int jt = 0; jt < 8; ++jt){
      const int j = lm + 16 * jt;
      bf16x8 av = __builtin_bit_cast(bf16x8,
          *(const uint4*)(W2lds + j * 64 + (kdw ^ (u32)((j & 7) << 2))));
#pragma unroll
      for(int st = 0; st < 4; ++st)
        acc1[jt][st] = __builtin_amdgcn_mfma_f32_16x16x32_bf16(av, bv[kt & 1][st], acc1[jt][st], 0, 0, 0);
    }
    __builtin_amdgcn_s_setprio(0);
  }

  // ---- transition: relu + pack directly into mid2 B-operand layout ----
  uint4 trq[4][4];   // [kt][st]
#pragma unroll
  for(int jt = 0; jt < 8; ++jt)
#pragma unroll
    for(int st = 0; st < 4; ++st){
      const u32 d0 = pk2(fmaxf(acc1[jt][st][0], 0.f), fmaxf(acc1[jt][st][1], 0.f));
      const u32 d1 = pk2(fmaxf(acc1[jt][st][2], 0.f), fmaxf(acc1[jt][st][3], 0.f));
      if(jt & 1){ trq[jt >> 1][st].z = d0; trq[jt >> 1][st].w = d1; }
      else      { trq[jt >> 1][st].x = d0; trq[jt >> 1][st].y = d1; }
    }

  // ---- mid2 + stage-4 fold, software-pipelined ----
  f32x4 aa[2][4];
  float p0 = 0.f, p1 = 0.f, p2 = 0.f, p3 = 0.f;
#pragma unroll
  for(int jt = 0; jt < 8; ++jt){
    const int j = lm + 16 * jt;
    const u32 sz = (u32)((j & 7) << 2);
    const u32* r = W3lds + j * 64;
    bf16x8 av[4];
#pragma unroll
    for(int kt = 0; kt < 4; ++kt)
      av[kt] = __builtin_bit_cast(bf16x8,
          *(const uint4*)(r + (((u32)(kt * 16 + lg * 4)) ^ sz)));
    const float4 bc = *(const float4*)(b3 + jt * 16 + lg * 4);
    const f32x4 cinit = {bc.x, bc.y, bc.z, bc.w};
#pragma unroll
    for(int st = 0; st < 4; ++st) aa[jt & 1][st] = cinit;
    if(jt > 0) FOLD(jt - 1);                 // previous tile's fold under this tile's MFMAs
    __builtin_amdgcn_s_setprio(1);
#pragma unroll
    for(int kt = 0; kt < 4; ++kt)
#pragma unroll
      for(int st = 0; st < 4; ++st)
        aa[jt & 1][st] = __builtin_amdgcn_mfma_f32_16x16x32_bf16(
            av[kt], __builtin_bit_cast(bf16x8, trq[kt][st]), aa[jt & 1][st], 0, 0, 0);
    __builtin_amdgcn_s_setprio(0);
  }
  FOLD(7);

  p0 += __shfl_xor(p0, 16, 64); p0 += __shfl_xor(p0, 32, 64);
  p1 += __shfl_xor(p1, 16, 64); p1 += __shfl_xor(p1, 32, 64);
  p2 += __shfl_xor(p2, 16, 64); p2 += __shfl_xor(p2, 32, 64);
  p3 += __shfl_xor(p3, 16, 64); p3 += __shfl_xor(p3, 32, 64);
  return (lg == 0) ? p0 : (lg == 1) ? p1 : (lg == 2) ? p2 : p3;
}

// ---------------- preprocess: fp32 weights -> bf16 LDS-image in d_ws ----------------
extern "C" __global__ void __launch_bounds__(256)
prep_kernel(const float* __restrict__ sW2, const float* __restrict__ sW3,
            const float* __restrict__ tW2, const float* __restrict__ tW3,
            u32* __restrict__ ws)
{
  const int b = blockIdx.x;
  const int layer = b >> 2, which = b & 3;
  const float* src = (which == 0 ? sW2 : which == 1 ? sW3 : which == 2 ? tW2 : tW3)
                     + layer * (WD * WD);
  u32* dst = ws + b * 8192;
  if(which & 1) stage_Wperm(src, dst, threadIdx.x);
  else          stage_Wnat (src, dst, threadIdx.x);
}

// ---------------- main kernel: double-buffered DMA staging ----------------
extern "C" __global__ void __launch_bounds__(512)
flow_dma(const float* __restrict__ x, const float* __restrict__ s_scale,
         const float* __restrict__ sW1, const float* __restrict__ sb1,
         const float* __restrict__ sb2, const float* __restrict__ sb3,
         const float* __restrict__ sW4, const float* __restrict__ sb4,
         const float* __restrict__ tW1, const float* __restrict__ tb1,
         const float* __restrict__ tb2, const float* __restrict__ tb3,
         const float* __restrict__ tW4, const float* __restrict__ tb4,
         const u32* __restrict__ wimg, float* __restrict__ out)
{
  __shared__ u32 Wbuf[2][16384];   // 128 KB: [buf][W2(8192) | W3(8192)]

  const int tid = threadIdx.x;
  const int lane = tid & 63, lg = lane >> 4, lm = lane & 15, wv = tid >> 6;
  const int gs = (int)blockIdx.x * 512 + tid;

  float2 ab = ((const float2*)x)[gs];
  float* scat = out + 2 * BATCH;
  float sv = 0.f;

  stage_dma(wimg, Wbuf[0], wv, lane);          // phase 0 slab

#pragma unroll 1
  for(int ph = 0; ph < 2 * LNUM; ++ph){
    const int i = ph >> 1, isT = ph & 1, parity = i & 1;
    asm volatile("s_waitcnt vmcnt(0)" ::: "memory");
    __syncthreads();                            // Wbuf[ph&1] fully landed
    if(ph < 2 * LNUM - 1)
      stage_dma(wimg + (ph + 1) * 16384, Wbuf[(ph + 1) & 1], wv, lane);

    const int off = i * WD;
    const float u = parity ? ab.y : ab.x;
    const u32* W2l = Wbuf[ph & 1];
    const u32* W3l = Wbuf[ph & 1] + 8192;

    if(!isT){
      float pre = mlp_full(u, W2l, W3l, sW1 + off, sb1 + off,
                           sb2 + off, sb3 + off, sW4 + off, lm, lg) + sb4[i];
      sv = s_scale[i] * tanhf(pre);
      scat[i * BATCH + gs] = sv;
    } else {
      float pre = mlp_full(u, W2l, W3l, tW1 + off, tb1 + off,
                           tb2 + off, tb3 + off, tW4 + off, lm, lg) + tb4[i];
      const float tv = tanhf(pre);
      const float e = expf(sv);
      if(parity) ab.x = e * ab.x + tv; else ab.y = e * ab.y + tv;
    }
  }

  ((float2*)out)[gs] = ab;
}

// ---------------- fallback: inline staging (R10 structure) ----------------
extern "C" __global__ void __launch_bounds__(256, 2)
flow_fb(const float* __restrict__ x, const float* __restrict__ s_scale,
        const float* __restrict__ sW1, const float* __restrict__ sb1,
        const float* __restrict__ sW2, const float* __restrict__ sb2,
        const float* __restrict__ sW3, const float* __restrict__ sb3,
        const float* __restrict__ sW4, const float* __restrict__ sb4,
        const float* __restrict__ tW1, const float* __restrict__ tb1,
        const float* __restrict__ tW2, const float* __restrict__ tb2,
        const float* __restrict__ tW3, const float* __restrict__ tb3,
        const float* __restrict__ tW4, const float* __restrict__ tb4,
        float* __restrict__ out)
{
  __shared__ u32 Wlds[2][8192];

  const int tid = threadIdx.x;
  const int lane = tid & 63, lg = lane >> 4, lm = lane & 15;
  const int gs = (int)blockIdx.x * 256 + tid;

  float2 ab = ((const float2*)x)[gs];
  float* scat = out + 2 * BATCH;

#pragma unroll 1
  for(int i = 0; i < LNUM; ++i){
    const int parity = i & 1;
    const float sc = s_scale[i];
    const int off = i * WD, offW = i * (WD * WD);

    __syncthreads();
    stage_Wnat (sW2 + offW, Wlds[0], tid);
    stage_Wperm(sW3 + offW, Wlds[1], tid);
    __syncthreads();
    const float u = parity ? ab.y : ab.x;
    float preS = mlp_full(u, Wlds[0], Wlds[1], sW1 + off, sb1 + off,
                          sb2 + off, sb3 + off, sW4 + off, lm, lg) + sb4[i];
    const float sv = sc * tanhf(preS);
    scat[i * BATCH + gs] = sv;

    __syncthreads();
    stage_Wnat (tW2 + offW, Wlds[0], tid);
    stage_Wperm(tW3 + offW, Wlds[1], tid);
    __syncthreads();
    float preT = mlp_full(u, Wlds[0], Wlds[1], tW1 + off, tb1 + off,
                          tb2 + off, tb3 + off, tW4 + off, lm, lg) + tb4[i];
    const float tv = tanhf(preT);
    const float e = expf(sv);
    if(parity) ab.x = e * ab.x + tv; else ab.y = e * ab.y + tv;
  }

  ((float2*)out)[gs] = ab;
}

extern "C" void kernel_launch(void* const* d_in, const int* in_sizes, int n_in,
                              void* d_out, int out_size, void* d_ws, size_t ws_size,
                              hipStream_t stream) {
  (void)in_sizes; (void)n_in; (void)out_size;
  const float* p[18];
  for(int k = 0; k < 18; ++k) p[k] = (const float*)d_in[k];

  const size_t need = (size_t)32 * 8192 * 4;   // 1 MiB bf16 weight image
  if(ws_size >= need){
    u32* ws = (u32*)d_ws;
    hipLaunchKernelGGL(prep_kernel, dim3(32), dim3(256), 0, stream,
                       p[4], p[6], p[12], p[14], ws);
    hipLaunchKernelGGL(flow_dma, dim3(BATCH / 512), dim3(512), 0, stream,
                       p[0], p[1], p[2], p[3], p[5], p[7], p[8], p[9],
                       p[10], p[11], p[13], p[15], p[16], p[17],
                       (const u32*)ws, (float*)d_out);
  } else {
    hipLaunchKernelGGL(flow_fb, dim3(BATCH / 256), dim3(256), 0, stream,
                       p[0], p[1], p[2], p[3], p[4], p[5], p[6], p[7], p[8], p[9],
                       p[10], p[11], p[12], p[13], p[14], p[15], p[16], p[17],
                       (float*)d_out);
  }
}